// Round 3
// baseline (84.080 us; speedup 1.0000x reference)
//
#include <hip/hip_runtime.h>
#include <math.h>

#define EPS_NORM 1e-8f
#define EPS_ERR  1e-8f

__device__ inline void norm3(float& x, float& y, float& z) {
    float nn = sqrtf(x*x + y*y + z*z);
    float inv = 1.0f / fmaxf(nn, EPS_NORM);
    x *= inv; y *= inv; z *= inv;
}

// F layout: frames[b,n,3(row d = xyz),3(col k = point a/b/c)], flat base = (bi*n+j)*9
__device__ inline void basis_from_frame(const float* __restrict__ F, size_t base,
                                        float* e /*[9]: e1,e2,e3 xyz*/, float* o /*[3]*/) {
    float ax = F[base + 0], bx = F[base + 1], cx = F[base + 2];
    float ay = F[base + 3], by = F[base + 4], cy = F[base + 5];
    float az = F[base + 6], bz = F[base + 7], cz = F[base + 8];
    float w1x = ax - bx, w1y = ay - by, w1z = az - bz;
    float w2x = cx - bx, w2y = cy - by, w2z = cz - bz;
    norm3(w1x, w1y, w1z);
    norm3(w2x, w2y, w2z);
    float e1x = w1x + w2x, e1y = w1y + w2y, e1z = w1z + w2z;
    float e2x = w2x - w1x, e2y = w2y - w1y, e2z = w2z - w1z;
    norm3(e1x, e1y, e1z);
    norm3(e2x, e2y, e2z);
    float e3x = e1y * e2z - e1z * e2y;
    float e3y = e1z * e2x - e1x * e2z;
    float e3z = e1x * e2y - e1y * e2x;
    e[0] = e1x; e[1] = e1y; e[2] = e1z;
    e[3] = e2x; e[4] = e2y; e[5] = e2z;
    e[6] = e3x; e[7] = e3y; e[8] = e3z;
    o[0] = bx * e1x + by * e1y + bz * e1z;
    o[1] = bx * e2x + by * e2y + bz * e2z;
    o[2] = bx * e3x + by * e3y + bz * e3z;
}

// One thread per (b,j) frame pair. SoA output: fd[c * total_bn + idx],
// c = 0..8: pred basis ep, 9..17: true basis et, 18..20: oc = op - ot.
__global__ __launch_bounds__(256) void frames_kernel(
    const float* __restrict__ predF, const float* __restrict__ trueF,
    float* __restrict__ fd, int total_bn)
{
    int idx = blockIdx.x * 256 + threadIdx.x;
    if (idx >= total_bn) return;
    float ep[9], op[3], et[9], ot[3];
    basis_from_frame(predF, (size_t)idx * 9, ep, op);
    basis_from_frame(trueF, (size_t)idx * 9, et, ot);
    #pragma unroll
    for (int k = 0; k < 9; ++k) fd[(size_t)k * total_bn + idx] = ep[k];
    #pragma unroll
    for (int k = 0; k < 9; ++k) fd[(size_t)(9 + k) * total_bn + idx] = et[k];
    #pragma unroll
    for (int k = 0; k < 3; ++k) fd[(size_t)(18 + k) * total_bn + idx] = op[k] - ot[k];
}

// Thread owns one j (coalesced writes + coalesced SoA frame loads),
// loops IT consecutive i's (block-uniform coord loads -> scalar loads).
template<int IT>
__global__ __launch_bounds__(256) void pair_err_kernel(
    const float* __restrict__ cp, const float* __restrict__ ct,
    const float* __restrict__ fd, float* __restrict__ out, int n, int total_bn)
{
    int j  = blockIdx.x * 256 + threadIdx.x;
    int bi = blockIdx.z;
    if (j >= n) return;
    int idx = bi * n + j;

    float f[21];
    #pragma unroll
    for (int c = 0; c < 21; ++c) f[c] = fd[(size_t)c * total_bn + idx];

    const int i0 = blockIdx.y * IT;
    const int iters = min(IT, n - i0);
    size_t obase = ((size_t)bi * n + i0) * n + j;
    size_t cbase = ((size_t)bi * n + i0) * 3;

    #pragma unroll 8
    for (int ii = 0; ii < iters; ++ii) {
        float px = cp[cbase + ii * 3 + 0], py = cp[cbase + ii * 3 + 1], pz = cp[cbase + ii * 3 + 2];
        float tx = ct[cbase + ii * 3 + 0], ty = ct[cbase + ii * 3 + 1], tz = ct[cbase + ii * 3 + 2];
        float d0 = px * f[0] + py * f[1] + pz * f[2] - (tx * f[ 9] + ty * f[10] + tz * f[11]) - f[18];
        float d1 = px * f[3] + py * f[4] + pz * f[5] - (tx * f[12] + ty * f[13] + tz * f[14]) - f[19];
        float d2 = px * f[6] + py * f[7] + pz * f[8] - (tx * f[15] + ty * f[16] + tz * f[17]) - f[20];
        out[obase + (size_t)ii * n] = sqrtf(d0 * d0 + d1 * d1 + d2 * d2 + EPS_ERR);
    }
}

extern "C" void kernel_launch(void* const* d_in, const int* in_sizes, int n_in,
                              void* d_out, int out_size, void* d_ws, size_t ws_size,
                              hipStream_t stream) {
    const float* pred_coords = (const float*)d_in[0];
    const float* true_coords = (const float*)d_in[1];
    const float* pred_frames = (const float*)d_in[2];
    const float* true_frames = (const float*)d_in[3];
    float* out = (float*)d_out;

    int total_bn = in_sizes[0] / 3;
    int n = (int)((long long)out_size / total_bn);
    int b = total_bn / n;

    float* fd = (float*)d_ws;  // 21 * total_bn floats, SoA

    int blocks1 = (total_bn + 255) / 256;
    frames_kernel<<<blocks1, 256, 0, stream>>>(pred_frames, true_frames, fd, total_bn);

    constexpr int IT = 32;
    dim3 grid((n + 255) / 256, (n + IT - 1) / IT, b);
    pair_err_kernel<IT><<<grid, 256, 0, stream>>>(pred_coords, true_coords, fd, out, n, total_bn);
}

// Round 4
// 81.333 us; speedup vs baseline: 1.0338x; 1.0338x over previous
//
#include <hip/hip_runtime.h>
#include <math.h>

#define EPS_NORM 1e-8f
#define EPS_ERR  1e-8f

__device__ inline void norm3(float& x, float& y, float& z) {
    float nn = sqrtf(x*x + y*y + z*z);
    float inv = 1.0f / fmaxf(nn, EPS_NORM);
    x *= inv; y *= inv; z *= inv;
}

// F layout: frames[b,n,3(row d = xyz),3(col k = point a/b/c)], flat base = (bi*n+j)*9
__device__ inline void basis_from_frame(const float* __restrict__ F, size_t base,
                                        float* e /*[9]*/, float* o /*[3]*/) {
    float ax = F[base + 0], bx = F[base + 1], cx = F[base + 2];
    float ay = F[base + 3], by = F[base + 4], cy = F[base + 5];
    float az = F[base + 6], bz = F[base + 7], cz = F[base + 8];
    float w1x = ax - bx, w1y = ay - by, w1z = az - bz;
    float w2x = cx - bx, w2y = cy - by, w2z = cz - bz;
    norm3(w1x, w1y, w1z);
    norm3(w2x, w2y, w2z);
    float e1x = w1x + w2x, e1y = w1y + w2y, e1z = w1z + w2z;
    float e2x = w2x - w1x, e2y = w2y - w1y, e2z = w2z - w1z;
    norm3(e1x, e1y, e1z);
    norm3(e2x, e2y, e2z);
    float e3x = e1y * e2z - e1z * e2y;
    float e3y = e1z * e2x - e1x * e2z;
    float e3z = e1x * e2y - e1y * e2x;
    e[0] = e1x; e[1] = e1y; e[2] = e1z;
    e[3] = e2x; e[4] = e2y; e[5] = e2z;
    e[6] = e3x; e[7] = e3y; e[8] = e3z;
    o[0] = bx * e1x + by * e1y + bz * e1z;
    o[1] = bx * e2x + by * e2y + bz * e2z;
    o[2] = bx * e3x + by * e3y + bz * e3z;
}

// f[0..8]=pred basis, f[9..17]=true basis, f[18..20]=op-ot (folded origins)
__device__ inline void frame21(const float* __restrict__ pF, const float* __restrict__ tF,
                               size_t base, float* f) {
    float e[9], o[3], e2[9], o2[3];
    basis_from_frame(pF, base, e, o);
    basis_from_frame(tF, base, e2, o2);
    #pragma unroll
    for (int k = 0; k < 9; ++k) f[k] = e[k];
    #pragma unroll
    for (int k = 0; k < 9; ++k) f[9 + k] = e2[k];
    #pragma unroll
    for (int k = 0; k < 3; ++k) f[18 + k] = o[k] - o2[k];
}

__device__ inline float perr(const float* f, float px, float py, float pz,
                             float tx, float ty, float tz) {
    float d0 = px * f[0] + py * f[1] + pz * f[2] - (tx * f[ 9] + ty * f[10] + tz * f[11]) - f[18];
    float d1 = px * f[3] + py * f[4] + pz * f[5] - (tx * f[12] + ty * f[13] + tz * f[14]) - f[19];
    float d2 = px * f[6] + py * f[7] + pz * f[8] - (tx * f[15] + ty * f[16] + tz * f[17]) - f[20];
    return sqrtf(d0 * d0 + d1 * d1 + d2 * d2 + EPS_ERR);
}

// Fused: thread owns 2 consecutive j's, recomputes both frame bases inline,
// loops IT i's with uniform coord loads, float2 coalesced stores. (even n)
template<int IT>
__global__ __launch_bounds__(256) void fused2_kernel(
    const float* __restrict__ cp, const float* __restrict__ ct,
    const float* __restrict__ pF, const float* __restrict__ tF,
    float* __restrict__ out, int n)
{
    const int bi = blockIdx.z;
    const int j0 = (blockIdx.x * 256 + threadIdx.x) * 2;
    if (j0 >= n) return;

    float fa[21], fb[21];
    frame21(pF, tF, ((size_t)bi * n + j0) * 9, fa);
    frame21(pF, tF, ((size_t)bi * n + j0 + 1) * 9, fb);

    const int i0 = blockIdx.y * IT;
    const int iters = min(IT, n - i0);
    const float* cpb = cp + ((size_t)bi * n + i0) * 3;
    const float* ctb = ct + ((size_t)bi * n + i0) * 3;
    float* ob = out + ((size_t)bi * n + i0) * n + j0;

    #pragma unroll 4
    for (int ii = 0; ii < iters; ++ii) {
        float px = cpb[ii * 3 + 0], py = cpb[ii * 3 + 1], pz = cpb[ii * 3 + 2];
        float tx = ctb[ii * 3 + 0], ty = ctb[ii * 3 + 1], tz = ctb[ii * 3 + 2];
        float2 r;
        r.x = perr(fa, px, py, pz, tx, ty, tz);
        r.y = perr(fb, px, py, pz, tx, ty, tz);
        *reinterpret_cast<float2*>(ob) = r;
        ob += n;
    }
}

// Scalar fallback for odd n (alignment/tail safety)
template<int IT>
__global__ __launch_bounds__(256) void fused1_kernel(
    const float* __restrict__ cp, const float* __restrict__ ct,
    const float* __restrict__ pF, const float* __restrict__ tF,
    float* __restrict__ out, int n)
{
    const int bi = blockIdx.z;
    const int j = blockIdx.x * 256 + threadIdx.x;
    if (j >= n) return;

    float fa[21];
    frame21(pF, tF, ((size_t)bi * n + j) * 9, fa);

    const int i0 = blockIdx.y * IT;
    const int iters = min(IT, n - i0);
    const float* cpb = cp + ((size_t)bi * n + i0) * 3;
    const float* ctb = ct + ((size_t)bi * n + i0) * 3;
    float* ob = out + ((size_t)bi * n + i0) * n + j;

    #pragma unroll 4
    for (int ii = 0; ii < iters; ++ii) {
        float px = cpb[ii * 3 + 0], py = cpb[ii * 3 + 1], pz = cpb[ii * 3 + 2];
        float tx = ctb[ii * 3 + 0], ty = ctb[ii * 3 + 1], tz = ctb[ii * 3 + 2];
        *ob = perr(fa, px, py, pz, tx, ty, tz);
        ob += n;
    }
}

extern "C" void kernel_launch(void* const* d_in, const int* in_sizes, int n_in,
                              void* d_out, int out_size, void* d_ws, size_t ws_size,
                              hipStream_t stream) {
    const float* pred_coords = (const float*)d_in[0];
    const float* true_coords = (const float*)d_in[1];
    const float* pred_frames = (const float*)d_in[2];
    const float* true_frames = (const float*)d_in[3];
    float* out = (float*)d_out;

    int total_bn = in_sizes[0] / 3;
    int n = (int)((long long)out_size / total_bn);
    int b = total_bn / n;

    constexpr int IT = 32;
    if ((n & 1) == 0) {
        int jthreads = n / 2;
        dim3 grid((jthreads + 255) / 256, (n + IT - 1) / IT, b);
        fused2_kernel<IT><<<grid, 256, 0, stream>>>(pred_coords, true_coords,
                                                    pred_frames, true_frames, out, n);
    } else {
        dim3 grid((n + 255) / 256, (n + IT - 1) / IT, b);
        fused1_kernel<IT><<<grid, 256, 0, stream>>>(pred_coords, true_coords,
                                                    pred_frames, true_frames, out, n);
    }
}